// Round 11
// baseline (40.746 us; speedup 1.0000x reference)
//
#include <hip/hip_runtime.h>

#define BATCH 16384
#define NU 1000000
#define TBR 64           // rows per block
#define MT 512           // threads, 8 waves

// Fragment-major LDS addressing: 16B slot s -> byte offset with 1/8 padding.
#define FSLOT(s) (((s) << 4) + (((s) >> 3) << 4))

typedef __attribute__((ext_vector_type(8))) short short8;
typedef __attribute__((ext_vector_type(4))) short short4v;
typedef __attribute__((ext_vector_type(4))) float f32x4;

__device__ __forceinline__ unsigned short f32_bf16(float f) {
    unsigned int u = __float_as_uint(f);
    u += 0x7FFF + ((u >> 16) & 1);   // RTNE
    return (unsigned short)(u >> 16);
}
__device__ __forceinline__ float bf16_f32(unsigned short h) {
    return __uint_as_float(((unsigned int)h) << 16);
}

__device__ __forceinline__ short8 cvt8(float4 a, float4 b) {
    short8 s;
    s[0] = (short)f32_bf16(a.x); s[1] = (short)f32_bf16(a.y);
    s[2] = (short)f32_bf16(a.z); s[3] = (short)f32_bf16(a.w);
    s[4] = (short)f32_bf16(b.x); s[5] = (short)f32_bf16(b.y);
    s[6] = (short)f32_bf16(b.z); s[7] = (short)f32_bf16(b.w);
    return s;
}

// Convert a 16-col strip of row-major fp32 W[k][n] into B-fragments.
// Coalesced loads (4 cache lines / wave-load), per-wave double-buffered
// fp32 scratch [32][17] (<=2-way banks on both write and read).
template<int KC>
__device__ __forceinline__ void conv_strip(const float* __restrict__ W, int N, int K,
                                           int cb, int lane, float* scr, short8* out) {
    const int lr = lane & 15, lh = lane >> 4;
    #pragma unroll
    for (int kc = 0; kc < KC; ++kc) {
        float* s = scr + (kc & 1) * 544;   // 544 floats = 2176 B per buffer
        float val[8];
        #pragma unroll
        for (int m = 0; m < 8; ++m) {
            int row = kc * 32 + m * 4 + lh;
            val[m] = (row < K) ? W[(size_t)row * N + cb + lr] : 0.f;
        }
        #pragma unroll
        for (int m = 0; m < 8; ++m)
            s[(m * 4 + lh) * 17 + lr] = val[m];
        short8 f;
        #pragma unroll
        for (int i = 0; i < 8; ++i)
            f[i] = (short)f32_bf16(s[(lh * 8 + i) * 17 + lr]);
        out[kc] = f;
    }
}

// ---- Single fused kernel: 256 blocks x 512 thr, 64 rows/block ----
__global__ __launch_bounds__(MT, 1) void wd_merged(
        const int* __restrict__ user, const int* __restrict__ item,
        const float* __restrict__ genre, const float* __restrict__ tag,
        const float* __restrict__ wide_W, const float* __restrict__ wide_b,
        const float* __restrict__ user_emb, const float* __restrict__ item_emb,
        const float* __restrict__ W0, const float* __restrict__ b0,
        const float* __restrict__ W1, const float* __restrict__ b1,
        const float* __restrict__ W2, const float* __restrict__ b2,
        const float* __restrict__ fW, const float* __restrict__ fb,
        float* __restrict__ out)
{
    __shared__ char sX[36864];                 // x  [4rt][8kc] frag-major
    __shared__ char sH0[36864];                // h0 frag-major; pre-barrier: conv scratch
    __shared__ char sH1[18432];                // h1 [4rt][4kc] frag-major
    __shared__ unsigned short sH2[TBR * 72];   // h2 bf16 (stride 72)
    __shared__ unsigned short sWide[TBR * 72]; // wide bf16 (stride 72)
    __shared__ float sFW[640];                 // fW fp32

    const int tid = threadIdx.x;
    const int row0 = blockIdx.x * TBR;

    const int wid = tid >> 6;     // 0..7
    const int lane = tid & 63;
    const int lr = lane & 15;
    const int lh = lane >> 4;
    const int aoff = FSLOT(lane); // lane-linear A-frag byte offset

    // Wave work assignments (r7 mapping)
    const int cb0 = wid * 32;          // L0: 32-col strip (2 x 16)
    const int cb1 = wid * 16;          // L1: 16-col strip
    const int cb2 = (wid & 3) * 16;    // L2: col strip
    const int rq2 = (wid >> 2) * 16;   // L2: row-quarter within 32-row half

    // ========== 1) Issue ALL gather loads (HBM latency starts now) ==========
    float4 xa[4], xb[4];
    #pragma unroll
    for (int it = 0; it < 4; ++it) {
        int q = tid + it * MT;
        int r = q >> 5, j = q & 31;
        int grow = row0 + r;
        float4 va = make_float4(0.f, 0.f, 0.f, 0.f);
        float4 vb = va;
        if (j < 8) {
            const float4* p = (const float4*)(user_emb + (size_t)user[grow] * 64);
            va = p[j * 2]; vb = p[j * 2 + 1];
        } else if (j < 16) {
            const float4* p = (const float4*)(item_emb + (size_t)item[grow] * 64);
            va = p[(j - 8) * 2]; vb = p[(j - 8) * 2 + 1];
        } else if (j == 16) {
            const float4* p = (const float4*)(genre + (size_t)grow * 20);
            va = p[0]; vb = p[1];
        } else if (j == 17) {
            const float4* p = (const float4*)(genre + (size_t)grow * 20);
            va = p[2]; vb = p[3];
        } else if (j == 18) {
            va = *(const float4*)(genre + (size_t)grow * 20 + 16);
            vb = *(const float4*)(tag + (size_t)grow * 100);
        } else if (j < 31) {
            const float4* p = (const float4*)(tag + (size_t)grow * 100 + 4);
            int jj = j - 19;
            va = p[jj * 2]; vb = p[jj * 2 + 1];
        } // j == 31: zero pad
        xa[it] = va; xb[it] = vb;
    }
    float4 wa[2], wb[2];
    {
        int j = tid & 15;
        #pragma unroll
        for (int it = 0; it < 2; ++it) {
            int q = tid + it * MT;
            int r = q >> 4;
            int grow = row0 + r;
            wa[it] = ((const float4*)(wide_W + (size_t)user[grow] * 64))[j];
            wb[it] = ((const float4*)(wide_W + (size_t)(NU + item[grow]) * 64))[j];
        }
    }
    float4 wc = ((const float4*)wide_b)[tid & 15];
    float4 fwv = make_float4(0.f, 0.f, 0.f, 0.f);
    if (tid < 160) fwv = ((const float4*)fW)[tid];
    float rb0[2];
    rb0[0] = b0[cb0 + lr]; rb0[1] = b0[cb0 + 16 + lr];
    float rb1 = b1[cb1 + lr];
    float rb2 = b2[cb2 + lr];

    // ========== 2) Weight conversion (coalesced; overlaps gather latency) ====
    // Per-wave scratch: 2 x 2176 B, overlaid on sH0 (dead until L0 epilogue).
    float* scr = (float*)(sH0 + wid * 4352);
    short8 B0[2][8], B1[8], B2f[4];
    conv_strip<8>(W0, 256, 248, cb0,      lane, scr, B0[0]);
    conv_strip<8>(W0, 256, 248, cb0 + 16, lane, scr, B0[1]);
    conv_strip<8>(W1, 128, 256, cb1,      lane, scr, B1);
    conv_strip<4>(W2,  64, 128, cb2,      lane, scr, B2f);

    // ========== 3) Write staged gathers to LDS (frag-major) ==========
    #pragma unroll
    for (int it = 0; it < 4; ++it) {
        int q = tid + it * MT;
        int r = q >> 5, j = q & 31;
        int slot = (((r >> 4) * 8 + (j >> 2)) << 6) + ((j & 3) << 4) + (r & 15);
        *(short8*)(sX + FSLOT(slot)) = cvt8(xa[it], xb[it]);
    }
    #pragma unroll
    for (int it = 0; it < 2; ++it) {
        int q = tid + it * MT;
        int r = q >> 4, j = q & 15;
        short4v o;
        o[0] = (short)f32_bf16(wa[it].x + wb[it].x + wc.x);
        o[1] = (short)f32_bf16(wa[it].y + wb[it].y + wc.y);
        o[2] = (short)f32_bf16(wa[it].z + wb[it].z + wc.z);
        o[3] = (short)f32_bf16(wa[it].w + wb[it].w + wc.w);
        *(short4v*)(sWide + r * 72 + j * 4) = o;
    }
    if (tid < 160) ((float4*)sFW)[tid] = fwv;

    // ---- Per-half layer bodies (h = 0: rows 0-31, h = 1: rows 32-63) ----
    auto do_L0 = [&](int h) {
        const int n0a = cb0 + lr, n0b = cb0 + 16 + lr;
        const int wkcA = n0a >> 5, wlhA = (n0a >> 3) & 3, welA = n0a & 7;
        const int wkcB = n0b >> 5, wlhB = (n0b >> 3) & 3, welB = n0b & 7;
        f32x4 acc[2][2];
        #pragma unroll
        for (int rt = 0; rt < 2; ++rt)
            #pragma unroll
            for (int t = 0; t < 2; ++t) acc[rt][t] = (f32x4)(0.f);
        #pragma unroll
        for (int kc = 0; kc < 8; ++kc) {
            short8 a[2];
            #pragma unroll
            for (int rt = 0; rt < 2; ++rt)
                a[rt] = *(const short8*)(sX + (h * 2 + rt) * 9216 + kc * 1152 + aoff);
            #pragma unroll
            for (int t = 0; t < 2; ++t)
                #pragma unroll
                for (int rt = 0; rt < 2; ++rt)
                    acc[rt][t] = __builtin_amdgcn_mfma_f32_16x16x32_bf16(a[rt], B0[t][kc], acc[rt][t], 0, 0, 0);
        }
        #pragma unroll
        for (int t = 0; t < 2; ++t) {
            const int wkc = t ? wkcB : wkcA, wlh = t ? wlhB : wlhA, wel = t ? welB : welA;
            #pragma unroll
            for (int rt = 0; rt < 2; ++rt)
                #pragma unroll
                for (int jj = 0; jj < 4; ++jj) {
                    int rlo = lh * 4 + jj;
                    float v = fmaxf(acc[rt][t][jj] + rb0[t], 0.f);
                    int slot = (((h * 2 + rt) * 8 + wkc) << 6) + (wlh << 4) + rlo;
                    *(unsigned short*)(sH0 + FSLOT(slot) + wel * 2) = f32_bf16(v);
                }
        }
    };

    auto do_L1 = [&](int h) {
        const int n1_ = cb1 + lr;
        const int wkc = n1_ >> 5, wlh = (n1_ >> 3) & 3, wel = n1_ & 7;
        f32x4 acc[2];
        acc[0] = (f32x4)(0.f); acc[1] = (f32x4)(0.f);
        #pragma unroll
        for (int kc = 0; kc < 8; ++kc) {
            #pragma unroll
            for (int rt = 0; rt < 2; ++rt) {
                short8 a = *(const short8*)(sH0 + (h * 2 + rt) * 9216 + kc * 1152 + aoff);
                acc[rt] = __builtin_amdgcn_mfma_f32_16x16x32_bf16(a, B1[kc], acc[rt], 0, 0, 0);
            }
        }
        #pragma unroll
        for (int rt = 0; rt < 2; ++rt)
            #pragma unroll
            for (int jj = 0; jj < 4; ++jj) {
                int rlo = lh * 4 + jj;
                float v = fmaxf(acc[rt][jj] + rb1, 0.f);
                int slot = (((h * 2 + rt) * 4 + wkc) << 6) + (wlh << 4) + rlo;
                *(unsigned short*)(sH1 + FSLOT(slot) + wel * 2) = f32_bf16(v);
            }
    };

    auto do_L2 = [&](int h) {
        const int rt2 = h * 2 + (wid >> 2);   // 16-row tile index 0..3
        f32x4 acc = (f32x4)(0.f);
        #pragma unroll
        for (int kc = 0; kc < 4; ++kc) {
            short8 a = *(const short8*)(sH1 + rt2 * 4608 + kc * 1152 + aoff);
            acc = __builtin_amdgcn_mfma_f32_16x16x32_bf16(a, B2f[kc], acc, 0, 0, 0);
        }
        #pragma unroll
        for (int jj = 0; jj < 4; ++jj) {
            int row = rt2 * 16 + lh * 4 + jj;
            sH2[row * 72 + cb2 + lr] = f32_bf16(fmaxf(acc[jj] + rb2, 0.f));
        }
    };

    // ---- Pipelined phase schedule ----
    __syncthreads();
    do_L0(0);
    __syncthreads();
    do_L0(1);
    do_L1(0);
    __syncthreads();
    do_L1(1);
    do_L2(0);
    __syncthreads();
    do_L2(1);
    __syncthreads();

    // ---- Final: [h2 | wide] @ fW + fb (fp32 VALU, LDS reads) ----
    if (tid < TBR * 5) {
        int r = tid / 5, c = tid - r * 5;
        float acc = fb[c];
        #pragma unroll
        for (int kq = 0; kq < 8; ++kq) {
            short8 h = *(const short8*)(sH2 + r * 72 + kq * 8);
            #pragma unroll
            for (int i = 0; i < 8; ++i)
                acc = fmaf(bf16_f32((unsigned short)h[i]), sFW[(kq * 8 + i) * 5 + c], acc);
        }
        #pragma unroll
        for (int kq = 0; kq < 8; ++kq) {
            short8 h = *(const short8*)(sWide + r * 72 + kq * 8);
            #pragma unroll
            for (int i = 0; i < 8; ++i)
                acc = fmaf(bf16_f32((unsigned short)h[i]), sFW[(64 + kq * 8 + i) * 5 + c], acc);
        }
        out[(size_t)(row0 + r) * 5 + c] = acc;
    }
}

extern "C" void kernel_launch(void* const* d_in, const int* in_sizes, int n_in,
                              void* d_out, int out_size, void* d_ws, size_t ws_size,
                              hipStream_t stream) {
    const int* user = (const int*)d_in[0];
    const int* item = (const int*)d_in[1];
    const float* genre = (const float*)d_in[2];
    const float* tag = (const float*)d_in[3];
    const float* wide_W = (const float*)d_in[4];
    const float* wide_b = (const float*)d_in[5];
    const float* user_emb = (const float*)d_in[6];
    const float* item_emb = (const float*)d_in[7];
    const float* W0 = (const float*)d_in[8];
    const float* b0 = (const float*)d_in[9];
    const float* W1 = (const float*)d_in[10];
    const float* b1 = (const float*)d_in[11];
    const float* W2 = (const float*)d_in[12];
    const float* b2 = (const float*)d_in[13];
    const float* fW = (const float*)d_in[14];
    const float* fb = (const float*)d_in[15];
    float* out = (float*)d_out;

    hipLaunchKernelGGL(wd_merged, dim3(BATCH / TBR), dim3(MT), 0, stream,
                       user, item, genre, tag, wide_W, wide_b, user_emb, item_emb,
                       W0, b0, W1, b1, W2, b2, fW, fb, out);
}

// Round 12
// 30.178 us; speedup vs baseline: 1.3502x; 1.3502x over previous
//
#include <hip/hip_runtime.h>

#define BATCH 16384
#define NU 1000000
#define TBR 64           // rows per block (mfma kernel)
#define MT 1024          // threads (mfma kernel), 16 waves -> 4 waves/SIMD
#define WSOFF0 0         // W0t [256][256] bf16
#define WSOFF1 65536     // W1t [128][256] bf16
#define WSOFF2 98304     // W2t [64][128]  bf16
#define WSREQ  212992    // bytes of ws needed

// Fragment-major LDS addressing: 16B slot s -> byte offset with 1/8 padding.
#define FSLOT(s) (((s) << 4) + (((s) >> 3) << 4))

typedef __attribute__((ext_vector_type(8))) short short8;
typedef __attribute__((ext_vector_type(4))) short short4v;
typedef __attribute__((ext_vector_type(4))) float f32x4;

__device__ __forceinline__ unsigned short f32_bf16(float f) {
    unsigned int u = __float_as_uint(f);
    u += 0x7FFF + ((u >> 16) & 1);   // RTNE
    return (unsigned short)(u >> 16);
}
__device__ __forceinline__ float bf16_f32(unsigned short h) {
    return __uint_as_float(((unsigned int)h) << 16);
}

__device__ __forceinline__ short8 cvt8(float4 a, float4 b) {
    short8 s;
    s[0] = (short)f32_bf16(a.x); s[1] = (short)f32_bf16(a.y);
    s[2] = (short)f32_bf16(a.z); s[3] = (short)f32_bf16(a.w);
    s[4] = (short)f32_bf16(b.x); s[5] = (short)f32_bf16(b.y);
    s[6] = (short)f32_bf16(b.z); s[7] = (short)f32_bf16(b.w);
    return s;
}

// Pack 4 relu(acc+bias) values into 4 bf16 (8B).
__device__ __forceinline__ short4v pack4(f32x4 acc, float4 bias) {
    short4v o;
    o[0] = (short)f32_bf16(fmaxf(acc[0] + bias.x, 0.f));
    o[1] = (short)f32_bf16(fmaxf(acc[1] + bias.y, 0.f));
    o[2] = (short)f32_bf16(fmaxf(acc[2] + bias.z, 0.f));
    o[3] = (short)f32_bf16(fmaxf(acc[3] + bias.w, 0.f));
    return o;
}

// ---- Weight-transpose slice: task g converts one u16x2 pair of Wt ----
__device__ __forceinline__ void prep_slice(int g, const float* __restrict__ W0,
                                           const float* __restrict__ W1,
                                           const float* __restrict__ W2,
                                           unsigned short* __restrict__ ws) {
    if (g >= 53248) return;
    int item = g >> 2, pair = g & 3;
    const float* src; unsigned short* dst; int n, kg, K, N, K2;
    if (item < 8192)       { src = W0; dst = ws + WSOFF0; n = item >> 5;            kg = item & 31; K = 248; N = 256; K2 = 256; }
    else if (item < 12288) { int r = item - 8192;  src = W1; dst = ws + WSOFF1; n = r >> 5; kg = r & 31; K = 256; N = 128; K2 = 256; }
    else                   { int r = item - 12288; src = W2; dst = ws + WSOFF2; n = r >> 4; kg = r & 15; K = 128; N = 64;  K2 = 128; }
    int k0 = kg * 8 + pair * 2;
    float v0 = (k0 < K)     ? src[(size_t)k0 * N + n]       : 0.f;
    float v1 = (k0 + 1 < K) ? src[(size_t)(k0 + 1) * N + n] : 0.f;
    unsigned int packed = (unsigned int)f32_bf16(v0) | ((unsigned int)f32_bf16(v1) << 16);
    *(unsigned int*)(dst + (size_t)n * K2 + k0) = packed;
}

// Prep kernel: 104 blocks x 512 thr.
__global__ void prep_simple(const float* __restrict__ W0, const float* __restrict__ W1,
                            const float* __restrict__ W2, unsigned short* __restrict__ ws) {
    prep_slice(blockIdx.x * 512 + threadIdx.x, W0, W1, W2, ws);
}

// ---- Main fused MFMA kernel: 256 blocks x 1024 thr, 64 rows/block ----
// Operand-swapped MFMA: acc = mfma(W_frag, x_frag) -> lane holds 4 consecutive
// OUTPUT COLS for one batch row -> packed 8B epilogue writes into frag-major LDS.
__global__ __launch_bounds__(MT) void wd_mfma(
        const int* __restrict__ user, const int* __restrict__ item,
        const float* __restrict__ genre, const float* __restrict__ tag,
        const float* __restrict__ wide_W, const float* __restrict__ wide_b,
        const float* __restrict__ user_emb, const float* __restrict__ item_emb,
        const float* __restrict__ b0, const float* __restrict__ b1,
        const float* __restrict__ b2,
        const float* __restrict__ fW, const float* __restrict__ fb,
        const unsigned short* __restrict__ ws, float* __restrict__ out)
{
    __shared__ char sX[36864];                 // x  [4rt][8kc] frag-major (padded)
    __shared__ char sH0[36864];                // h0 [4rt][8kc] frag-major
    __shared__ char sH1[18432];                // h1 [4rt][4kc] frag-major
    __shared__ unsigned short sH2[TBR * 72];   // h2 bf16 (stride 72)
    __shared__ unsigned short sWide[TBR * 72]; // wide bf16 (stride 72)
    __shared__ float sFW[640];                 // fW fp32

    const int tid = threadIdx.x;
    const int row0 = blockIdx.x * TBR;
    const unsigned short* w0t = ws + WSOFF0;
    const unsigned short* w1t = ws + WSOFF1;
    const unsigned short* w2t = ws + WSOFF2;

    const int wid = tid >> 6;     // 0..15
    const int lane = tid & 63;
    const int lr = lane & 15;     // batch-row within 16-tile (D col)
    const int lh = lane >> 4;     // k-chunk 0..3 / out-col group (D row /4)
    const int aoff = FSLOT(lane); // per-lane fragment byte offset (lane-linear)

    // Wave work assignments
    const int cb0 = wid * 16;              // L0: 16 col-strips of 16
    const int s1 = wid & 7, h1b = wid >> 3; // L1: 8 strips x 2 batch-halves
    const int cb1 = s1 * 16;
    const int s2 = wid & 3, q2 = wid >> 2; // L2: 4 strips x 4 batch-quarters
    const int cb2 = s2 * 16;

    // ---- Prefetch L0 W-fragments + biases ----
    short8 B0[8];
    #pragma unroll
    for (int kc = 0; kc < 8; ++kc)
        B0[kc] = *(const short8*)(w0t + (size_t)(cb0 + lr) * 256 + kc * 32 + lh * 8);
    float4 bf0 = *(const float4*)(b0 + cb0 + lh * 4);
    float4 bf1 = *(const float4*)(b1 + cb1 + lh * 4);
    float4 bf2 = *(const float4*)(b2 + cb2 + lh * 4);

    // Epilogue write constants (out-col group g = cb + lh*4)
    const int g0 = cb0 + lh * 4, kc0w = g0 >> 5, lh0w = (g0 >> 3) & 3, hf0 = (lh & 1) * 8;
    const int g1 = cb1 + lh * 4, kc1w = g1 >> 5, lh1w = (g1 >> 3) & 3, hf1 = (lh & 1) * 8;

    // ---- Stage x (bf16, frag-major) + wide path ----
    #pragma unroll
    for (int it = 0; it < 2; ++it) {
        int q = tid + it * MT;
        int r = q >> 5, j = q & 31;
        int grow = row0 + r;
        float4 va = make_float4(0.f, 0.f, 0.f, 0.f);
        float4 vb = va;
        if (j < 8) {
            const float4* p = (const float4*)(user_emb + (size_t)user[grow] * 64);
            va = p[j * 2]; vb = p[j * 2 + 1];
        } else if (j < 16) {
            const float4* p = (const float4*)(item_emb + (size_t)item[grow] * 64);
            va = p[(j - 8) * 2]; vb = p[(j - 8) * 2 + 1];
        } else if (j == 16) {
            const float4* p = (const float4*)(genre + (size_t)grow * 20);
            va = p[0]; vb = p[1];
        } else if (j == 17) {
            const float4* p = (const float4*)(genre + (size_t)grow * 20);
            va = p[2]; vb = p[3];
        } else if (j == 18) {
            va = *(const float4*)(genre + (size_t)grow * 20 + 16);
            vb = *(const float4*)(tag + (size_t)grow * 100);
        } else if (j < 31) {
            const float4* p = (const float4*)(tag + (size_t)grow * 100 + 4);
            int jj = j - 19;
            va = p[jj * 2]; vb = p[jj * 2 + 1];
        } // j == 31: zero pad (k 248..255)
        int slot = (((r >> 4) * 8 + (j >> 2)) << 6) + ((j & 3) << 4) + (r & 15);
        *(short8*)(sX + FSLOT(slot)) = cvt8(va, vb);
    }
    {
        int r = tid >> 4, j = tid & 15;
        int grow = row0 + r;
        float4 a = ((const float4*)(wide_W + (size_t)user[grow] * 64))[j];
        float4 b = ((const float4*)(wide_W + (size_t)(NU + item[grow]) * 64))[j];
        float4 c = ((const float4*)wide_b)[j];
        short4v o;
        o[0] = (short)f32_bf16(a.x + b.x + c.x);
        o[1] = (short)f32_bf16(a.y + b.y + c.y);
        o[2] = (short)f32_bf16(a.z + b.z + c.z);
        o[3] = (short)f32_bf16(a.w + b.w + c.w);
        *(short4v*)(sWide + r * 72 + j * 4) = o;
    }
    if (tid < 160) {
        ((float4*)sFW)[tid] = ((const float4*)fW)[tid];
    }
    __syncthreads();

    // ---- Layer 0: h0^T tiles = W0strip x x-frag (wave = 16-col strip, 4 batch-tiles) ----
    {
        f32x4 acc[4];
        #pragma unroll
        for (int rt = 0; rt < 4; ++rt) acc[rt] = (f32x4)(0.f);
        #pragma unroll
        for (int kc = 0; kc < 8; ++kc) {
            #pragma unroll
            for (int rt = 0; rt < 4; ++rt) {
                short8 x = *(const short8*)(sX + rt * 9216 + kc * 1152 + aoff);
                acc[rt] = __builtin_amdgcn_mfma_f32_16x16x32_bf16(B0[kc], x, acc[rt], 0, 0, 0);
            }
        }
        #pragma unroll
        for (int rt = 0; rt < 4; ++rt) {
            int slot = ((rt * 8 + kc0w) << 6) + (lh0w << 4) + lr;
            *(short4v*)(sH0 + FSLOT(slot) + hf0) = pack4(acc[rt], bf0);
        }
        __syncthreads();
    }

    // ---- Layer 1: h1^T = W1strip x h0-frag (wave = 16-col strip x 32-batch half) ----
    {
        f32x4 acc[2];
        acc[0] = (f32x4)(0.f); acc[1] = (f32x4)(0.f);
        #pragma unroll
        for (int kc = 0; kc < 8; ++kc) {
            short8 bf = *(const short8*)(w1t + (size_t)(cb1 + lr) * 256 + kc * 32 + lh * 8);
            #pragma unroll
            for (int rt = 0; rt < 2; ++rt) {
                int rt2 = h1b * 2 + rt;
                short8 h = *(const short8*)(sH0 + rt2 * 9216 + kc * 1152 + aoff);
                acc[rt] = __builtin_amdgcn_mfma_f32_16x16x32_bf16(bf, h, acc[rt], 0, 0, 0);
            }
        }
        #pragma unroll
        for (int rt = 0; rt < 2; ++rt) {
            int rt2 = h1b * 2 + rt;
            int slot = ((rt2 * 4 + kc1w) << 6) + (lh1w << 4) + lr;
            *(short4v*)(sH1 + FSLOT(slot) + hf1) = pack4(acc[rt], bf1);
        }
        __syncthreads();
    }

    // ---- Layer 2: h2^T = W2strip x h1-frag (wave = 16-col strip x 16-batch quarter) ----
    {
        f32x4 acc = (f32x4)(0.f);
        #pragma unroll
        for (int kc = 0; kc < 4; ++kc) {
            short8 bf = *(const short8*)(w2t + (size_t)(cb2 + lr) * 128 + kc * 32 + lh * 8);
            short8 h = *(const short8*)(sH1 + q2 * 4608 + kc * 1152 + aoff);
            acc = __builtin_amdgcn_mfma_f32_16x16x32_bf16(bf, h, acc, 0, 0, 0);
        }
        int row = q2 * 16 + lr;
        *(short4v*)(sH2 + row * 72 + cb2 + lh * 4) = pack4(acc, bf2);
        __syncthreads();
    }

    // ---- Final: [h2 | wide] @ fW + fb (fp32 VALU, LDS reads) ----
    if (tid < TBR * 5) {
        int r = tid / 5, c = tid - r * 5;
        float acc = fb[c];
        #pragma unroll
        for (int kq = 0; kq < 8; ++kq) {
            short8 h = *(const short8*)(sH2 + r * 72 + kq * 8);
            #pragma unroll
            for (int i = 0; i < 8; ++i)
                acc = fmaf(bf16_f32((unsigned short)h[i]), sFW[(kq * 8 + i) * 5 + c], acc);
        }
        #pragma unroll
        for (int kq = 0; kq < 8; ++kq) {
            short8 h = *(const short8*)(sWide + r * 72 + kq * 8);
            #pragma unroll
            for (int i = 0; i < 8; ++i)
                acc = fmaf(bf16_f32((unsigned short)h[i]), sFW[(64 + kq * 8 + i) * 5 + c], acc);
        }
        out[(size_t)(row0 + r) * 5 + c] = acc;
    }
}

// ================= fp32 fallback (used if ws too small) =================
#define NTHR 256
#define TB 32

__device__ __forceinline__ void fma4(float4& a, float s, const float4& w) {
    a.x = fmaf(s, w.x, a.x); a.y = fmaf(s, w.y, a.y);
    a.z = fmaf(s, w.z, a.z); a.w = fmaf(s, w.w, a.w);
}
__device__ __forceinline__ float4 add4(const float4& a, const float4& b) {
    return make_float4(a.x + b.x, a.y + b.y, a.z + b.z, a.w + b.w);
}
__device__ __forceinline__ float4 relu4(const float4& a) {
    return make_float4(fmaxf(a.x, 0.f), fmaxf(a.y, 0.f), fmaxf(a.z, 0.f), fmaxf(a.w, 0.f));
}

__global__ void wd_fused(const int* __restrict__ user, const int* __restrict__ item,
                         const float* __restrict__ genre, const float* __restrict__ tag,
                         const float* __restrict__ wide_W, const float* __restrict__ wide_b,
                         const float* __restrict__ user_emb, const float* __restrict__ item_emb,
                         const float* __restrict__ W0, const float* __restrict__ b0,
                         const float* __restrict__ W1, const float* __restrict__ b1,
                         const float* __restrict__ W2, const float* __restrict__ b2,
                         const float* __restrict__ fW, const float* __restrict__ fb,
                         float* __restrict__ out)
{
    __shared__ float sA[TB * 248];
    __shared__ float sB[TB * 256];
    __shared__ float sC[TB * 64];

    const int tid = threadIdx.x;
    const int row0 = blockIdx.x * TB;

    for (int q = tid; q < TB * 62; q += NTHR) {
        int r = q / 62, j = q - r * 62, grow = row0 + r;
        float4 v;
        if (j < 16) v = reinterpret_cast<const float4*>(user_emb + (size_t)user[grow] * 64)[j];
        else if (j < 32) v = reinterpret_cast<const float4*>(item_emb + (size_t)item[grow] * 64)[j - 16];
        else if (j < 37) v = reinterpret_cast<const float4*>(genre + (size_t)grow * 20)[j - 32];
        else v = reinterpret_cast<const float4*>(tag + (size_t)grow * 100)[j - 37];
        *reinterpret_cast<float4*>(sA + r * 248 + j * 4) = v;
    }
    for (int q = tid; q < TB * 16; q += NTHR) {
        int r = q >> 4, j = q & 15, grow = row0 + r;
        float4 a = reinterpret_cast<const float4*>(wide_W + (size_t)user[grow] * 64)[j];
        float4 b = reinterpret_cast<const float4*>(wide_W + (size_t)(NU + item[grow]) * 64)[j];
        float4 c = reinterpret_cast<const float4*>(wide_b)[j];
        *reinterpret_cast<float4*>(sC + r * 64 + j * 4) =
            make_float4(a.x + b.x + c.x, a.y + b.y + c.y, a.z + b.z + c.z, a.w + b.w + c.w);
    }
    __syncthreads();
    {
        const int cg = tid & 63, r0 = (tid >> 6) * 8;
        float4 acc[8];
        #pragma unroll
        for (int r = 0; r < 8; ++r) acc[r] = make_float4(0.f, 0.f, 0.f, 0.f);
        for (int k = 0; k < 248; k += 4) {
            const float4* wp = reinterpret_cast<const float4*>(W0 + (size_t)k * 256) + cg;
            float4 w0 = wp[0], w1 = wp[64], w2 = wp[128], w3 = wp[192];
            #pragma unroll
            for (int r = 0; r < 8; ++r) {
                float4 xv = *reinterpret_cast<const float4*>(sA + (r0 + r) * 248 + k);
                fma4(acc[r], xv.x, w0); fma4(acc[r], xv.y, w1);
                fma4(acc[r], xv.z, w2); fma4(acc[r], xv.w, w3);
            }
        }
        float4 bb = reinterpret_cast<const float4*>(b0)[cg];
        #pragma unroll
        for (int r = 0; r < 8; ++r)
            *reinterpret_cast<float4*>(sB + (r0 + r) * 256 + cg * 4) = relu4(add4(acc[r], bb));
    }
    __syncthreads();
    {
        const int cg = tid & 31, r0 = (tid >> 5) * 4;
        float4 acc[4];
        #pragma unroll
        for (int r = 0; r < 4; ++r) acc[r] = make_float4(0.f, 0.f, 0.f, 0.f);
        for (int k = 0; k < 256; k += 4) {
            const float4* wp = reinterpret_cast<const float4*>(W1 + (size_t)k * 128) + cg;
            float4 w0 = wp[0], w1 = wp[32], w2 = wp[64], w3 = wp[96];
            #pragma unroll
            for (int r = 0; r < 4; ++r) {
                float4 xv = *reinterpret_cast<const float4*>(sB + (r0 + r) * 256 + k);
                fma4(acc[r], xv.x, w0); fma4(acc[r], xv.y, w1);
                fma4(acc[r], xv.z, w2); fma4(acc[r], xv.w, w3);
            }
        }
        float4 bb = reinterpret_cast<const float4*>(b1)[cg];
        #pragma unroll
        for (int r = 0; r < 4; ++r)
            *reinterpret_cast<float4*>(sA + (r0 + r) * 128 + cg * 4) = relu4(add4(acc[r], bb));
    }
    __syncthreads();
    {
        const int cg = tid & 15, r0 = (tid >> 4) * 2;
        float4 acc[2];
        acc[0] = make_float4(0.f, 0.f, 0.f, 0.f); acc[1] = acc[0];
        for (int k = 0; k < 128; k += 4) {
            const float4* wp = reinterpret_cast<const float4*>(W2 + (size_t)k * 64) + cg;
            float4 w0 = wp[0], w1 = wp[16], w2 = wp[32], w3 = wp[48];
            #pragma unroll
            for (int r = 0; r < 2; ++r) {
                float4 xv = *reinterpret_cast<const float4*>(sA + (r0 + r) * 128 + k);
                fma4(acc[r], xv.x, w0); fma4(acc[r], xv.y, w1);
                fma4(acc[r], xv.z, w2); fma4(acc[r], xv.w, w3);
            }
        }
        float4 bb = reinterpret_cast<const float4*>(b2)[cg];
        #pragma unroll
        for (int r = 0; r < 2; ++r)
            *reinterpret_cast<float4*>(sB + (r0 + r) * 64 + cg * 4) = relu4(add4(acc[r], bb));
    }
    __syncthreads();
    if (tid < TB * 5) {
        int r = tid / 5, c = tid - r * 5;
        float acc = fb[c];
        for (int k = 0; k < 64; ++k) acc = fmaf(sB[r * 64 + k], fW[k * 5 + c], acc);
        for (int k = 0; k < 64; ++k) acc = fmaf(sC[r * 64 + k], fW[(64 + k) * 5 + c], acc);
        out[(size_t)(row0 + r) * 5 + c] = acc;
    }
}

extern "C" void kernel_launch(void* const* d_in, const int* in_sizes, int n_in,
                              void* d_out, int out_size, void* d_ws, size_t ws_size,
                              hipStream_t stream) {
    const int* user = (const int*)d_in[0];
    const int* item = (const int*)d_in[1];
    const float* genre = (const float*)d_in[2];
    const float* tag = (const float*)d_in[3];
    const float* wide_W = (const float*)d_in[4];
    const float* wide_b = (const float*)d_in[5];
    const float* user_emb = (const float*)d_in[6];
    const float* item_emb = (const float*)d_in[7];
    const float* W0 = (const float*)d_in[8];
    const float* b0 = (const float*)d_in[9];
    const float* W1 = (const float*)d_in[10];
    const float* b1 = (const float*)d_in[11];
    const float* W2 = (const float*)d_in[12];
    const float* b2 = (const float*)d_in[13];
    const float* fW = (const float*)d_in[14];
    const float* fb = (const float*)d_in[15];
    float* out = (float*)d_out;

    if (ws_size >= (size_t)WSREQ) {
        unsigned short* ws = (unsigned short*)d_ws;
        hipLaunchKernelGGL(prep_simple, dim3(104), dim3(512), 0, stream,
                           W0, W1, W2, ws);
        hipLaunchKernelGGL(wd_mfma, dim3(BATCH / TBR), dim3(MT), 0, stream,
                           user, item, genre, tag, wide_W, wide_b, user_emb, item_emb,
                           b0, b1, b2, fW, fb, ws, out);
    } else {
        hipLaunchKernelGGL(wd_fused, dim3(BATCH / TB), dim3(NTHR), 0, stream,
                           user, item, genre, tag, wide_W, wide_b, user_emb, item_emb,
                           W0, b0, W1, b1, W2, b2, fW, fb, out);
    }
}